// Round 4
// baseline (1851.235 us; speedup 1.0000x reference)
//
#include <hip/hip_runtime.h>
#include <hip/hip_bf16.h>

typedef __attribute__((ext_vector_type(8))) short short8v;
typedef __attribute__((ext_vector_type(8))) unsigned short ushort8v;
typedef __attribute__((ext_vector_type(4))) float f32x4;

#define N_NBR 65536
#define INIT_DIM 512
#define HID 1024
#define BM 64
#define NBLK 1024   // one block per M-tile; each block does all 3 types

static __device__ __forceinline__ unsigned short f2bf(float f) {
  unsigned int u = __float_as_uint(f);
  u += 0x7fff + ((u >> 16) & 1);   // round-to-nearest-even
  return (unsigned short)(u >> 16);
}

// Relayout W (3x [1024 n][512 k] f32) into MFMA-fragment order bf16:
// for tile block (t, nb 0..63, ks 0..15), the 1KB a wave reads is contiguous:
//   out[(((t*64+nb)*16)+ks)*512 + l*8 + j] = W_t[nb*16 + (l&15)][ks*32 + (l>>4)*8 + j]
__global__ __launch_bounds__(256) void k_convw(const float* __restrict__ wa,
                                               const float* __restrict__ wb,
                                               const float* __restrict__ wc,
                                               unsigned short* __restrict__ out) {
  int g = blockIdx.x * 256 + threadIdx.x;   // 0..196607
  int l = g & 63;
  int blk = g >> 6;            // (t*64+nb)*16+ks
  int ks = blk & 15;
  int tnb = blk >> 4;
  int t = tnb >> 6;
  int nb = tnb & 63;
  const float* src = (t == 0) ? wa : (t == 1) ? wb : wc;
  int n = nb * 16 + (l & 15);
  int k0 = ks * 32 + (l >> 4) * 8;
  const f32x4* p = (const f32x4*)(src + (size_t)n * INIT_DIM + k0);
  f32x4 a = p[0], b = p[1];
  ushort8v v;
  v[0]=f2bf(a.x); v[1]=f2bf(a.y); v[2]=f2bf(a.z); v[3]=f2bf(a.w);
  v[4]=f2bf(b.x); v[5]=f2bf(b.y); v[6]=f2bf(b.z); v[7]=f2bf(b.w);
  *(ushort8v*)(out + (size_t)g * 8) = v;
}

// Main: block bx handles M-tile bx of ALL 3 types, accumulating relu-column-
// sums in registers. B is read from fragment-ordered wbf (contiguous 1KB wave
// reads) with a 1-deep register double-buffer; A gather uses nontemporal
// loads so W stays L2-resident. One 4KB partial store per block, no atomics.
__global__ __launch_bounds__(256, 2) void k_main(
    const float* __restrict__ fa, const float* __restrict__ fb, const float* __restrict__ fc,
    const int* __restrict__ na, const int* __restrict__ nb_, const int* __restrict__ nc__,
    const float* __restrict__ b1a, const float* __restrict__ b1b, const float* __restrict__ b1c,
    const unsigned short* __restrict__ wbf,   // [3][64 nb][16 ks][512] fragment-ordered bf16
    float* __restrict__ partials) {           // [NBLK][HID]
  __shared__ __align__(16) unsigned short Asm[BM * INIT_DIM];  // 64 KB
  __shared__ int idxs[3 * BM];

  int bx = blockIdx.x;
  int tid = threadIdx.x;
  if (tid < 3 * BM) {
    int tt = tid >> 6;
    const int* nbr = (tt == 0) ? na : (tt == 1) ? nb_ : nc__;
    idxs[tid] = nbr[bx * BM + (tid & 63)];
  }

  int wave = tid >> 6;
  int lane = tid & 63;
  int l15 = lane & 15, lg = lane >> 4;

  // A ds_read swizzle algebra: addr = r*1024 + ((ks*64 + lg*16) ^ m), m=(r&7)<<4.
  // r&7 == l15&7 (r = mf*16+l15), so m is mf-independent. Decompose:
  //   addr = r*1024 + lo + (ks*64 ^ hi), lo = (lg*16)^(m&48), hi = m&64.
  unsigned int m_  = (unsigned)(l15 & 7) << 4;
  unsigned int lo_ = ((unsigned)(lg * 16)) ^ (m_ & 48u);
  unsigned int hi_ = m_ & 64u;
  unsigned int abase = (unsigned)l15 * 1024u + lo_;

  float sacc[4][4] = {};        // [nc_][nf]

  for (int t = 0; t < 3; ++t) {
    const float* feat = (t == 0) ? fa : (t == 1) ? fb : fc;
    const float* bias = (t == 0) ? b1a : (t == 1) ? b1b : b1c;
    const unsigned short* Wf = wbf + (size_t)t * (HID * INIT_DIM);

    __syncthreads();   // idxs visible (t=0) / prior MFMA reads of Asm done (t>0)

    // Stage A: 64 rows x 512 f32 -> bf16 into LDS with XOR swizzle (nt loads).
    #pragma unroll
    for (int it = 0; it < 16; ++it) {
      int i = it * 256 + tid;     // chunk of 8 floats
      int r = i >> 6;
      int ck = i & 63;
      const float* rowp = feat + (size_t)idxs[t * BM + r] * INIT_DIM + ck * 8;
      f32x4 a = __builtin_nontemporal_load((const f32x4*)rowp);
      f32x4 b = __builtin_nontemporal_load(((const f32x4*)rowp) + 1);
      ushort8v v;
      v[0]=f2bf(a.x); v[1]=f2bf(a.y); v[2]=f2bf(a.z); v[3]=f2bf(a.w);
      v[4]=f2bf(b.x); v[5]=f2bf(b.y); v[6]=f2bf(b.z); v[7]=f2bf(b.w);
      int byte = r * 1024 + ((ck * 16) ^ ((r & 7) << 4));
      *(ushort8v*)((char*)Asm + byte) = v;
    }
    __syncthreads();

    #pragma unroll
    for (int nc_ = 0; nc_ < 4; ++nc_) {
      // Fragment-ordered B base pointers: n_blk = wave*16 + nc_*4 + nf.
      const unsigned short* pB[4];
      #pragma unroll
      for (int nf = 0; nf < 4; ++nf)
        pB[nf] = Wf + ((size_t)(wave * 16 + nc_ * 4 + nf) << 13) + lane * 8;

      f32x4 acc[4][4] = {};      // [mf][nf]
      short8v Bc[4], Bn[4];
      #pragma unroll
      for (int nf = 0; nf < 4; ++nf) Bc[nf] = *(const short8v*)(pB[nf]);

      #pragma unroll
      for (int ks = 0; ks < 16; ++ks) {
        if (ks < 15) {
          #pragma unroll
          for (int nf = 0; nf < 4; ++nf)
            Bn[nf] = *(const short8v*)(pB[nf] + ((ks + 1) << 9));
        }
        short8v Af[4];
        #pragma unroll
        for (int mf = 0; mf < 4; ++mf) {
          unsigned int addr = abase + (unsigned)(mf * 16384) + (((unsigned)(ks * 64)) ^ hi_);
          Af[mf] = *(const short8v*)((const char*)Asm + addr);
        }
        #pragma unroll
        for (int mf = 0; mf < 4; ++mf)
          #pragma unroll
          for (int nf = 0; nf < 4; ++nf)
            acc[mf][nf] = __builtin_amdgcn_mfma_f32_16x16x32_bf16(Af[mf], Bc[nf], acc[mf][nf], 0, 0, 0);
        if (ks < 15) {
          #pragma unroll
          for (int nf = 0; nf < 4; ++nf) Bc[nf] = Bn[nf];
        }
      }

      // Fold bias + relu + per-lane row-sum into sacc.
      #pragma unroll
      for (int nf = 0; nf < 4; ++nf) {
        int n = wave * 256 + nc_ * 64 + nf * 16 + l15;
        float b = bias[n];
        float s = 0.f;
        #pragma unroll
        for (int mf = 0; mf < 4; ++mf)
          #pragma unroll
          for (int r = 0; r < 4; ++r) {
            float v = acc[mf][nf][r] + b;
            s += (v > 0.f) ? v : 0.f;
          }
        sacc[nc_][nf] += s;
      }
    }
  }

  // Cross-lane reduce (rows) and ONE partial store per column per block.
  #pragma unroll
  for (int nc_ = 0; nc_ < 4; ++nc_) {
    #pragma unroll
    for (int nf = 0; nf < 4; ++nf) {
      float s = sacc[nc_][nf];
      s += __shfl_xor(s, 16);
      s += __shfl_xor(s, 32);
      if (lg == 0) {
        int n = wave * 256 + nc_ * 64 + nf * 16 + l15;
        partials[(size_t)bx * HID + n] = s;
      }
    }
  }
}

// Column-sum of partials [NBLK][HID] -> acc[HID]. 16 blocks x 64 cols.
__global__ __launch_bounds__(256) void k_reduce(const float* __restrict__ partials,
                                                float* __restrict__ acc) {
  __shared__ float red[4][64];
  int tid = threadIdx.x;
  int c = tid & 63, rg = tid >> 6;
  int col = blockIdx.x * 64 + c;
  float s = 0.f;
  #pragma unroll 4
  for (int r = rg; r < NBLK; r += 4)
    s += partials[(size_t)r * HID + col];
  red[rg][c] = s;
  __syncthreads();
  if (rg == 0) acc[col] = red[0][c] + red[1][c] + red[2][c] + red[3][c];
}

// pooled = acc/196608 ; feat_all = relu ; logits = feat_all @ Wc.T + bc
__global__ __launch_bounds__(256) void k_final(const float* __restrict__ acc,
                                               const float* __restrict__ Wc,
                                               const float* __restrict__ bc,
                                               float* __restrict__ out) {
  __shared__ float fall[HID];
  int tid = threadIdx.x;
  const float inv = 1.f / (3.f * (float)N_NBR);
  for (int i = tid; i < HID; i += 256) {
    float p = acc[i] * inv;
    fall[i] = (p > 0.f) ? p : 0.f;
  }
  __syncthreads();
  int o = tid >> 2, q = tid & 3;
  const f32x4* w = (const f32x4*)(Wc + (size_t)o * HID + q * 256);
  const f32x4* f = (const f32x4*)(fall + q * 256);
  float s = 0.f;
  #pragma unroll 4
  for (int k = 0; k < 64; ++k) {
    f32x4 wv = w[k], fv = f[k];
    s += wv.x * fv.x + wv.y * fv.y + wv.z * fv.z + wv.w * fv.w;
  }
  s += __shfl_xor(s, 1);
  s += __shfl_xor(s, 2);
  if (q == 0) out[o] = s + bc[o];
}

extern "C" void kernel_launch(void* const* d_in, const int* in_sizes, int n_in,
                              void* d_out, int out_size, void* d_ws, size_t ws_size,
                              hipStream_t stream) {
  // inputs: 0 feat(unused), 1 fa, 2 na, 3 W1a, 4 b1a, 5 fb, 6 nb, 7 W1b, 8 b1b,
  //         9 fc, 10 nc, 11 W1c, 12 b1c, 13 Wc, 14 bc
  const float* fa  = (const float*)d_in[1];
  const int*   na  = (const int*)d_in[2];
  const float* W1a = (const float*)d_in[3];
  const float* b1a = (const float*)d_in[4];
  const float* fb  = (const float*)d_in[5];
  const int*   nb  = (const int*)d_in[6];
  const float* W1b = (const float*)d_in[7];
  const float* b1b = (const float*)d_in[8];
  const float* fc  = (const float*)d_in[9];
  const int*   nc  = (const int*)d_in[10];
  const float* W1c = (const float*)d_in[11];
  const float* b1c = (const float*)d_in[12];
  const float* Wc  = (const float*)d_in[13];
  const float* bc  = (const float*)d_in[14];
  float* out = (float*)d_out;

  float* acc = (float*)d_ws;                                          // 1024 f32
  unsigned short* wbf = (unsigned short*)((char*)d_ws + 4096);        // 3 MB bf16 fragment-ordered
  float* partials = (float*)((char*)d_ws + 4096 + 3 * HID * INIT_DIM * sizeof(unsigned short)); // 4 MB

  k_convw<<<768, 256, 0, stream>>>(W1a, W1b, W1c, wbf);
  k_main<<<NBLK, 256, 0, stream>>>(fa, fb, fc, na, nb, nc, b1a, b1b, b1c, wbf, partials);
  k_reduce<<<16, 256, 0, stream>>>(partials, acc);
  k_final<<<1, 256, 0, stream>>>(acc, Wc, bc, out);
}

// Round 5
// 329.129 us; speedup vs baseline: 5.6246x; 5.6246x over previous
//
#include <hip/hip_runtime.h>
#include <hip/hip_bf16.h>

typedef __attribute__((ext_vector_type(8))) short short8v;
typedef __attribute__((ext_vector_type(8))) unsigned short ushort8v;
typedef __attribute__((ext_vector_type(4))) float f32x4;

#define N_NBR 65536
#define INIT_DIM 512
#define HID 1024
#define BM 64
#define NBLK 1024   // one block per M-tile; each block does all 3 types

static __device__ __forceinline__ unsigned short f2bf(float f) {
  unsigned int u = __float_as_uint(f);
  u += 0x7fff + ((u >> 16) & 1);   // round-to-nearest-even
  return (unsigned short)(u >> 16);
}

// Relayout W (3x [1024 n][512 k] f32) into MFMA-fragment order bf16:
// for tile block (t, nb 0..63, ks 0..15), the 1KB a wave reads is contiguous:
//   out[(((t*64+nb)*16)+ks)*512 + l*8 + j] = W_t[nb*16 + (l&15)][ks*32 + (l>>4)*8 + j]
__global__ __launch_bounds__(256) void k_convw(const float* __restrict__ wa,
                                               const float* __restrict__ wb,
                                               const float* __restrict__ wc,
                                               unsigned short* __restrict__ out) {
  int g = blockIdx.x * 256 + threadIdx.x;   // 0..196607
  int l = g & 63;
  int blk = g >> 6;            // (t*64+nb)*16+ks
  int ks = blk & 15;
  int tnb = blk >> 4;
  int t = tnb >> 6;
  int nb = tnb & 63;
  const float* src = (t == 0) ? wa : (t == 1) ? wb : wc;
  int n = nb * 16 + (l & 15);
  int k0 = ks * 32 + (l >> 4) * 8;
  const f32x4* p = (const f32x4*)(src + (size_t)n * INIT_DIM + k0);
  f32x4 a = p[0], b = p[1];
  ushort8v v;
  v[0]=f2bf(a.x); v[1]=f2bf(a.y); v[2]=f2bf(a.z); v[3]=f2bf(a.w);
  v[4]=f2bf(b.x); v[5]=f2bf(b.y); v[6]=f2bf(b.z); v[7]=f2bf(b.w);
  *(ushort8v*)(out + (size_t)g * 8) = v;
}

// Main: block bx handles M-tile bx of ALL 3 types, accumulating relu-column-
// sums in registers. B is read from fragment-ordered wbf (contiguous 1KB wave
// reads) with a 1-deep register double-buffer; A gather uses nontemporal
// loads so W stays L2-resident. One 4KB partial store per block, no atomics.
// NOTE: no min-waves bound — R4's (256,2) capped VGPR at 128 and spilled
// (5.5 GB scratch writes). LDS (66.5KB) limits us to 2 blocks/CU anyway.
__global__ __launch_bounds__(256) void k_main(
    const float* __restrict__ fa, const float* __restrict__ fb, const float* __restrict__ fc,
    const int* __restrict__ na, const int* __restrict__ nb_, const int* __restrict__ nc__,
    const float* __restrict__ b1a, const float* __restrict__ b1b, const float* __restrict__ b1c,
    const unsigned short* __restrict__ wbf,   // [3][64 nb][16 ks][512] fragment-ordered bf16
    float* __restrict__ partials) {           // [NBLK][HID]
  __shared__ __align__(16) unsigned short Asm[BM * INIT_DIM];  // 64 KB
  __shared__ int idxs[3 * BM];

  int bx = blockIdx.x;
  int tid = threadIdx.x;
  if (tid < 3 * BM) {
    int tt = tid >> 6;
    const int* nbr = (tt == 0) ? na : (tt == 1) ? nb_ : nc__;
    idxs[tid] = nbr[bx * BM + (tid & 63)];
  }

  int wave = tid >> 6;
  int lane = tid & 63;
  int l15 = lane & 15, lg = lane >> 4;

  // A ds_read swizzle algebra: addr = r*1024 + ((ks*64 + lg*16) ^ m), m=(r&7)<<4.
  // r&7 == l15&7 (r = mf*16+l15), so m is mf-independent. Decompose:
  //   addr = r*1024 + lo + (ks*64 ^ hi), lo = (lg*16)^(m&48), hi = m&64.
  unsigned int m_  = (unsigned)(l15 & 7) << 4;
  unsigned int lo_ = ((unsigned)(lg * 16)) ^ (m_ & 48u);
  unsigned int hi_ = m_ & 64u;
  unsigned int abase = (unsigned)l15 * 1024u + lo_;

  float sacc[4][4] = {};        // [nc_][nf]

  for (int t = 0; t < 3; ++t) {
    const float* feat = (t == 0) ? fa : (t == 1) ? fb : fc;
    const float* bias = (t == 0) ? b1a : (t == 1) ? b1b : b1c;
    const unsigned short* Wf = wbf + (size_t)t * (HID * INIT_DIM);

    __syncthreads();   // idxs visible (t=0) / prior MFMA reads of Asm done (t>0)

    // Stage A: 64 rows x 512 f32 -> bf16 into LDS with XOR swizzle (nt loads).
    #pragma unroll
    for (int it = 0; it < 16; ++it) {
      int i = it * 256 + tid;     // chunk of 8 floats
      int r = i >> 6;
      int ck = i & 63;
      const float* rowp = feat + (size_t)idxs[t * BM + r] * INIT_DIM + ck * 8;
      f32x4 a = __builtin_nontemporal_load((const f32x4*)rowp);
      f32x4 b = __builtin_nontemporal_load(((const f32x4*)rowp) + 1);
      ushort8v v;
      v[0]=f2bf(a.x); v[1]=f2bf(a.y); v[2]=f2bf(a.z); v[3]=f2bf(a.w);
      v[4]=f2bf(b.x); v[5]=f2bf(b.y); v[6]=f2bf(b.z); v[7]=f2bf(b.w);
      int byte = r * 1024 + ((ck * 16) ^ ((r & 7) << 4));
      *(ushort8v*)((char*)Asm + byte) = v;
    }
    __syncthreads();

    #pragma unroll
    for (int nc_ = 0; nc_ < 4; ++nc_) {
      // Fragment-ordered B base pointers: n_blk = wave*16 + nc_*4 + nf.
      const unsigned short* pB[4];
      #pragma unroll
      for (int nf = 0; nf < 4; ++nf)
        pB[nf] = Wf + ((size_t)(wave * 16 + nc_ * 4 + nf) << 13) + lane * 8;

      f32x4 acc[4][4] = {};      // [mf][nf]
      short8v Bc[4], Bn[4];
      #pragma unroll
      for (int nf = 0; nf < 4; ++nf) Bc[nf] = *(const short8v*)(pB[nf]);

      #pragma unroll
      for (int ks = 0; ks < 16; ++ks) {
        if (ks < 15) {
          #pragma unroll
          for (int nf = 0; nf < 4; ++nf)
            Bn[nf] = *(const short8v*)(pB[nf] + ((ks + 1) << 9));
        }
        short8v Af[4];
        #pragma unroll
        for (int mf = 0; mf < 4; ++mf) {
          unsigned int addr = abase + (unsigned)(mf * 16384) + (((unsigned)(ks * 64)) ^ hi_);
          Af[mf] = *(const short8v*)((const char*)Asm + addr);
        }
        #pragma unroll
        for (int mf = 0; mf < 4; ++mf)
          #pragma unroll
          for (int nf = 0; nf < 4; ++nf)
            acc[mf][nf] = __builtin_amdgcn_mfma_f32_16x16x32_bf16(Af[mf], Bc[nf], acc[mf][nf], 0, 0, 0);
        if (ks < 15) {
          #pragma unroll
          for (int nf = 0; nf < 4; ++nf) Bc[nf] = Bn[nf];
        }
      }

      // Fold bias + relu + per-lane row-sum into sacc.
      #pragma unroll
      for (int nf = 0; nf < 4; ++nf) {
        int n = wave * 256 + nc_ * 64 + nf * 16 + l15;
        float b = bias[n];
        float s = 0.f;
        #pragma unroll
        for (int mf = 0; mf < 4; ++mf)
          #pragma unroll
          for (int r = 0; r < 4; ++r) {
            float v = acc[mf][nf][r] + b;
            s += (v > 0.f) ? v : 0.f;
          }
        sacc[nc_][nf] += s;
      }
    }
  }

  // Cross-lane reduce (rows) and ONE partial store per column per block.
  #pragma unroll
  for (int nc_ = 0; nc_ < 4; ++nc_) {
    #pragma unroll
    for (int nf = 0; nf < 4; ++nf) {
      float s = sacc[nc_][nf];
      s += __shfl_xor(s, 16);
      s += __shfl_xor(s, 32);
      if (lg == 0) {
        int n = wave * 256 + nc_ * 64 + nf * 16 + l15;
        partials[(size_t)bx * HID + n] = s;
      }
    }
  }
}

// Column-sum of partials [NBLK][HID] -> acc[HID]. 16 blocks x 64 cols.
__global__ __launch_bounds__(256) void k_reduce(const float* __restrict__ partials,
                                                float* __restrict__ acc) {
  __shared__ float red[4][64];
  int tid = threadIdx.x;
  int c = tid & 63, rg = tid >> 6;
  int col = blockIdx.x * 64 + c;
  float s = 0.f;
  #pragma unroll 4
  for (int r = rg; r < NBLK; r += 4)
    s += partials[(size_t)r * HID + col];
  red[rg][c] = s;
  __syncthreads();
  if (rg == 0) acc[col] = red[0][c] + red[1][c] + red[2][c] + red[3][c];
}

// pooled = acc/196608 ; feat_all = relu ; logits = feat_all @ Wc.T + bc
__global__ __launch_bounds__(256) void k_final(const float* __restrict__ acc,
                                               const float* __restrict__ Wc,
                                               const float* __restrict__ bc,
                                               float* __restrict__ out) {
  __shared__ float fall[HID];
  int tid = threadIdx.x;
  const float inv = 1.f / (3.f * (float)N_NBR);
  for (int i = tid; i < HID; i += 256) {
    float p = acc[i] * inv;
    fall[i] = (p > 0.f) ? p : 0.f;
  }
  __syncthreads();
  int o = tid >> 2, q = tid & 3;
  const f32x4* w = (const f32x4*)(Wc + (size_t)o * HID + q * 256);
  const f32x4* f = (const f32x4*)(fall + q * 256);
  float s = 0.f;
  #pragma unroll 4
  for (int k = 0; k < 64; ++k) {
    f32x4 wv = w[k], fv = f[k];
    s += wv.x * fv.x + wv.y * fv.y + wv.z * fv.z + wv.w * fv.w;
  }
  s += __shfl_xor(s, 1);
  s += __shfl_xor(s, 2);
  if (q == 0) out[o] = s + bc[o];
}

extern "C" void kernel_launch(void* const* d_in, const int* in_sizes, int n_in,
                              void* d_out, int out_size, void* d_ws, size_t ws_size,
                              hipStream_t stream) {
  // inputs: 0 feat(unused), 1 fa, 2 na, 3 W1a, 4 b1a, 5 fb, 6 nb, 7 W1b, 8 b1b,
  //         9 fc, 10 nc, 11 W1c, 12 b1c, 13 Wc, 14 bc
  const float* fa  = (const float*)d_in[1];
  const int*   na  = (const int*)d_in[2];
  const float* W1a = (const float*)d_in[3];
  const float* b1a = (const float*)d_in[4];
  const float* fb  = (const float*)d_in[5];
  const int*   nb  = (const int*)d_in[6];
  const float* W1b = (const float*)d_in[7];
  const float* b1b = (const float*)d_in[8];
  const float* fc  = (const float*)d_in[9];
  const int*   nc  = (const int*)d_in[10];
  const float* W1c = (const float*)d_in[11];
  const float* b1c = (const float*)d_in[12];
  const float* Wc  = (const float*)d_in[13];
  const float* bc  = (const float*)d_in[14];
  float* out = (float*)d_out;

  float* acc = (float*)d_ws;                                          // 1024 f32
  unsigned short* wbf = (unsigned short*)((char*)d_ws + 4096);        // 3 MB bf16 fragment-ordered
  float* partials = (float*)((char*)d_ws + 4096 + 3 * HID * INIT_DIM * sizeof(unsigned short)); // 4 MB

  k_convw<<<768, 256, 0, stream>>>(W1a, W1b, W1c, wbf);
  k_main<<<NBLK, 256, 0, stream>>>(fa, fb, fc, na, nb, nc, b1a, b1b, b1c, wbf, partials);
  k_reduce<<<16, 256, 0, stream>>>(partials, acc);
  k_final<<<1, 256, 0, stream>>>(acc, Wc, bc, out);
}